// Round 18
// baseline (598.384 us; speedup 1.0000x reference)
//
#include <hip/hip_runtime.h>
#include <cmath>

// Multi-scale residual VQ, round 18 = R17 + 1024-thread fuse_k.
// R17 insight: fuse grid 256 = 1 block/CU -> LDS "2 blocks/CU" headroom moot;
// each fuse is one 8-wave barrier-serialized block (33us vs ~8us floor).
// R18: 16 waves/block (4/SIMD), channel-QUARTERS in A/conv, phase B as
// (c,h)-row threads (contiguous row loads replace 64 scattered b32 reads).
// argmin path unchanged from R17 (MFMA, proven).

#define BB 64
#define CC 32
#define HH 16
#define VV 4096
#define NTOT (BB*CC*HH*HH)   // 524288

typedef __attribute__((ext_vector_type(8))) short bf16x8;
typedef __attribute__((ext_vector_type(4))) float f32x4;

__device__ __forceinline__ double cubicw(double x) {
    x = fabs(x);
    const double a = -0.75;
    if (x <= 1.0) return ((a + 2.0) * x - (a + 3.0)) * x * x + 1.0;
    if (x < 2.0)  return (((a * x - 5.0 * a) * x + 8.0 * a) * x - 4.0 * a);
    return 0.0;
}

__device__ __forceinline__ unsigned int ordf(float d) {
    unsigned int b = __float_as_uint(d);
    return (b & 0x80000000u) ? ~b : (b | 0x80000000u);
}

__device__ __forceinline__ short f2bf(float x) {
    unsigned u = __float_as_uint(x);
    unsigned r = (u + 0x7fffu + ((u >> 16) & 1u)) >> 16;
    return (short)r;
}
__device__ __forceinline__ float bf2f(short h) {
    return __uint_as_float(((unsigned)(unsigned short)h) << 16);
}

__global__ void init_k(const float* __restrict__ f, const float* __restrict__ E,
                       float* __restrict__ f_rest, float* __restrict__ f_hat,
                       float* __restrict__ e2, float* __restrict__ z,
                       float* __restrict__ es) {
    int i = blockIdx.x * 256 + threadIdx.x;
    if (i < NTOT) { f_rest[i] = f[i]; f_hat[i] = 0.f; }
    if (i < VV) {
        float s = 0.f;
        unsigned short* ew = es ? (unsigned short*)(es + (size_t)i * 48) : (unsigned short*)0;
        #pragma unroll
        for (int c = 0; c < CC; ++c) {
            float x = E[i * CC + c];
            s += x * x;
            if (ew) {
                short h = f2bf(x); float rm = x - bf2f(h);
                short m = f2bf(rm); float rl = rm - bf2f(m);
                short l = f2bf(rl);
                ew[c] = (unsigned short)h;
                ew[32 + c] = (unsigned short)m;
                ew[64 + c] = (unsigned short)l;
            }
        }
        e2[i] = s;
    }
    if (i < BB * CC) {
        const float* src = f + (size_t)i * (HH * HH);
        float s = 0.f;
        for (int j = 0; j < HH * HH; ++j) s += src[j];
        z[i] = s * (1.0f / 256.0f);
    }
}

__global__ __launch_bounds__(256, 4) void argsmall_k(const float* __restrict__ z,
        const float* __restrict__ E, const float* __restrict__ e2,
        unsigned long long* __restrict__ bestk, int M, int G, int gsz) {
    const int t = threadIdx.x;
    int m = blockIdx.x * 64 + (t & 63);
    int w = __builtin_amdgcn_readfirstlane(t >> 6);
    int wg = blockIdx.y * 4 + w;
    int v0 = wg * gsz;
    float zr[CC]; float z2 = 0.f;
    const float4* zp = (const float4*)(z + (size_t)m * CC);
    #pragma unroll
    for (int c4 = 0; c4 < 8; ++c4) {
        float4 v = zp[c4];
        zr[c4*4+0] = v.x; zr[c4*4+1] = v.y; zr[c4*4+2] = v.z; zr[c4*4+3] = v.w;
        z2 += v.x*v.x + v.y*v.y + v.z*v.z + v.w*v.w;
    }
    const float* e = E + (size_t)v0 * CC;
    float best = 3.4e38f; int bv = v0;
    for (int v = v0; v < v0 + gsz; v += 2, e += 2 * CC) {
        float a0 = 0.f, a1 = 0.f, b0 = 0.f, b1 = 0.f;
        #pragma unroll
        for (int c = 0; c < CC; c += 2) {
            a0 = fmaf(zr[c],   e[c],      a0);
            a1 = fmaf(zr[c+1], e[c+1],    a1);
            b0 = fmaf(zr[c],   e[CC+c],   b0);
            b1 = fmaf(zr[c+1], e[CC+c+1], b1);
        }
        float dA = fmaf(-2.f, a0 + a1, z2 + e2[v]);
        float dB = fmaf(-2.f, b0 + b1, z2 + e2[v+1]);
        if (dA < best) { best = dA; bv = v; }
        if (dB < best) { best = dB; bv = v + 1; }
    }
    bestk[(size_t)m * G + wg] = ((unsigned long long)ordf(best) << 32) |
                                (unsigned long long)(unsigned int)bv;
}

// MFMA argmin (R17-proven).
__global__ __launch_bounds__(256, 4) void argmf_k(const float* __restrict__ z,
        const float* __restrict__ es, const float* __restrict__ e2,
        unsigned long long* __restrict__ bestk, int M, int G, int gsz) {
    __shared__ float s_es[128 * 52];
    __shared__ float s_e2[128];
    const int t = threadIdx.x;
    const int g = blockIdx.y;
    const int v0 = g * gsz;
    for (int i = t; i < gsz * 12; i += 256) {
        int row = i / 12, part = i - row * 12;
        *(float4*)&s_es[row * 52 + part * 4] =
            *(const float4*)&es[(size_t)(v0 + row) * 48 + part * 4];
    }
    for (int i = t; i < gsz; i += 256) s_e2[i] = e2[v0 + i];

    const int lane = t & 63;
    const int w = t >> 6;
    const int n = lane & 15, kq = lane >> 4;

    int tb[2]; bf16x8 ah[2], am[2], al[2]; float z2r[2][4];
    #pragma unroll
    for (int pt = 0; pt < 2; ++pt) {
        int tb0 = blockIdx.x * 128 + w * 32 + pt * 16;
        if (tb0 > M - 16) tb0 = M - 16;
        tb[pt] = tb0;
        const float* zp = z + (size_t)(tb0 + n) * CC + kq * 8;
        float4 zA = *(const float4*)zp, zB = *(const float4*)(zp + 4);
        float zv[8] = {zA.x, zA.y, zA.z, zA.w, zB.x, zB.y, zB.z, zB.w};
        float p2 = 0.f;
        #pragma unroll
        for (int j = 0; j < 8; ++j) {
            float x = zv[j];
            p2 = fmaf(x, x, p2);
            short h = f2bf(x); float rm = x - bf2f(h);
            short m = f2bf(rm); float rl = rm - bf2f(m);
            short l = f2bf(rl);
            ah[pt][j] = h; am[pt][j] = m; al[pt][j] = l;
        }
        p2 += __shfl_xor(p2, 16);
        p2 += __shfl_xor(p2, 32);
        #pragma unroll
        for (int r = 0; r < 4; ++r)
            z2r[pt][r] = __shfl(p2, kq * 4 + r);
    }
    __syncthreads();

    float bd[2][4]; int bc[2][4];
    #pragma unroll
    for (int pt = 0; pt < 2; ++pt)
        #pragma unroll
        for (int r = 0; r < 4; ++r) { bd[pt][r] = 3.4e38f; bc[pt][r] = 0; }

    const int nct = gsz >> 4;
    for (int ct = 0; ct < nct; ++ct) {
        int base = (ct * 16 + n) * 52 + kq * 4;
        bf16x8 eh = *(const bf16x8*)&s_es[base];
        bf16x8 em = *(const bf16x8*)&s_es[base + 16];
        bf16x8 el = *(const bf16x8*)&s_es[base + 32];
        float e2c = s_e2[ct * 16 + n];
        #pragma unroll
        for (int pt = 0; pt < 2; ++pt) {
            f32x4 C = {0.f, 0.f, 0.f, 0.f};
            C = __builtin_amdgcn_mfma_f32_16x16x32_bf16(ah[pt], eh, C, 0, 0, 0);
            C = __builtin_amdgcn_mfma_f32_16x16x32_bf16(ah[pt], em, C, 0, 0, 0);
            C = __builtin_amdgcn_mfma_f32_16x16x32_bf16(am[pt], eh, C, 0, 0, 0);
            C = __builtin_amdgcn_mfma_f32_16x16x32_bf16(ah[pt], el, C, 0, 0, 0);
            C = __builtin_amdgcn_mfma_f32_16x16x32_bf16(al[pt], eh, C, 0, 0, 0);
            C = __builtin_amdgcn_mfma_f32_16x16x32_bf16(am[pt], em, C, 0, 0, 0);
            #pragma unroll
            for (int r = 0; r < 4; ++r) {
                float d = fmaf(-2.f, C[r], z2r[pt][r] + e2c);
                if (d < bd[pt][r]) { bd[pt][r] = d; bc[pt][r] = ct; }
            }
        }
    }
    #pragma unroll
    for (int pt = 0; pt < 2; ++pt) {
        #pragma unroll
        for (int r = 0; r < 4; ++r) {
            int v = v0 + bc[pt][r] * 16 + n;
            unsigned long long k = ((unsigned long long)ordf(bd[pt][r]) << 32) |
                                   (unsigned long long)(unsigned int)v;
            #pragma unroll
            for (int msk = 1; msk < 16; msk <<= 1) {
                unsigned long long o = __shfl_xor(k, msk);
                if (o < k) k = o;
            }
            if (n == 0)
                bestk[(size_t)(tb[pt] + kq * 4 + r) * G + g] = k;
        }
    }
}

// Fallback big-scale argmin (R12-proven).
__global__ __launch_bounds__(256, 4) void argbig_k(const float* __restrict__ z,
        const float* __restrict__ E, const float* __restrict__ e2,
        unsigned long long* __restrict__ bestk, int M, int G, int gsz) {
    __shared__ float s_e[128 * CC];
    __shared__ float s_e2[128];
    const int T = gridDim.x * 256;
    const int g = blockIdx.y;
    const int v0 = g * gsz;
    {
        const float4* src = (const float4*)(E + (size_t)v0 * CC);
        float4* dst = (float4*)s_e;
        for (int i = threadIdx.x; i < gsz * 8; i += 256) dst[i] = src[i];
        if (threadIdx.x < gsz) s_e2[threadIdx.x] = e2[v0 + threadIdx.x];
    }
    int   mm[2];
    bool  act[2];
    float zr[2][CC];
    float z2[2];
    #pragma unroll
    for (int pt = 0; pt < 2; ++pt) {
        int m0 = blockIdx.x * 256 + threadIdx.x + pt * T;
        act[pt] = (m0 < M);
        int m = act[pt] ? m0 : M - 1;
        mm[pt] = m;
        const float4* zp = (const float4*)(z + (size_t)m * CC);
        float zz = 0.f;
        #pragma unroll
        for (int c4 = 0; c4 < 8; ++c4) {
            float4 v = zp[c4];
            zr[pt][c4*4+0] = v.x; zr[pt][c4*4+1] = v.y;
            zr[pt][c4*4+2] = v.z; zr[pt][c4*4+3] = v.w;
            zz += v.x*v.x + v.y*v.y + v.z*v.z + v.w*v.w;
        }
        z2[pt] = zz;
    }
    __syncthreads();
    float best[2]; int bv[2];
    #pragma unroll
    for (int pt = 0; pt < 2; ++pt) { best[pt] = 3.4e38f; bv[pt] = v0; }
    const float4* ev = (const float4*)s_e;
    for (int vi = 0; vi < gsz; ++vi, ev += 8) {
        float4 e0 = ev[0], e1 = ev[1], e2v = ev[2], e3 = ev[3];
        float4 e4 = ev[4], e5 = ev[5], e6v = ev[6], e7 = ev[7];
        float ef[CC] = {e0.x,e0.y,e0.z,e0.w, e1.x,e1.y,e1.z,e1.w,
                        e2v.x,e2v.y,e2v.z,e2v.w, e3.x,e3.y,e3.z,e3.w,
                        e4.x,e4.y,e4.z,e4.w, e5.x,e5.y,e5.z,e5.w,
                        e6v.x,e6v.y,e6v.z,e6v.w, e7.x,e7.y,e7.z,e7.w};
        float a0 = 0.f, a1 = 0.f, b0 = 0.f, b1 = 0.f;
        #pragma unroll
        for (int c = 0; c < CC; c += 2) {
            a0 = fmaf(zr[0][c],   ef[c],   a0);
            a1 = fmaf(zr[0][c+1], ef[c+1], a1);
            b0 = fmaf(zr[1][c],   ef[c],   b0);
            b1 = fmaf(zr[1][c+1], ef[c+1], b1);
        }
        float e2c = s_e2[vi];
        float dA = fmaf(-2.f, a0 + a1, z2[0] + e2c);
        float dB = fmaf(-2.f, b0 + b1, z2[1] + e2c);
        int v = v0 + vi;
        if (dA < best[0]) { best[0] = dA; bv[0] = v; }
        if (dB < best[1]) { best[1] = dB; bv[1] = v; }
    }
    #pragma unroll
    for (int pt = 0; pt < 2; ++pt)
        if (act[pt])
            bestk[(size_t)mm[pt] * G + g] =
                ((unsigned long long)ordf(best[pt]) << 32) |
                (unsigned long long)(unsigned int)bv[pt];
}

// Fused, 1024 threads (16 waves = 4/SIMD): channel-quarters in A and conv,
// phase B as (c,h)-row threads. Traffic identical to R16; 2x the waves.
__global__ __launch_bounds__(1024) void fuse_k(const unsigned long long* __restrict__ bestk,
                      const float* __restrict__ E,
                      const float* __restrict__ pw, const float* __restrict__ pb,
                      float* __restrict__ f_hat, float* __restrict__ f_rest,
                      float* __restrict__ z_next,
                      int pn, int G, int TPP, int kphi, int pnn) {
    __shared__ float s_buf[CC * 18 * 20];
    __shared__ float s_pw[CC * 9 * 8];      // transposed: [ci*9+tap][col]
    __shared__ float s_part[3 * 256 * 9];   // conv partials, quarters 1..3
    __shared__ int   s_idx[256];
    __shared__ float s_w[HH][4];
    __shared__ int   s_j[HH][4];
    __shared__ unsigned long long s_red[1024];
    const int t    = threadIdx.x;
    const int cog  = blockIdx.x;
    const int b    = blockIdx.y;
    const int P    = pn * pn;
    const int qt   = t >> 8;      // 0..3
    const int tl   = t & 255;

    // ---- phase 0: reduce over G keys per point ----
    {
        int p = t / TPP, sub = t - p * TPP;
        unsigned long long bk = ~0ull;
        if (p < P) {
            const unsigned long long* kp = bestk + (size_t)(b * P + p) * G;
            for (int gg = sub; gg < G; gg += TPP) {
                unsigned long long o = kp[gg];
                if (o < bk) bk = o;
            }
        }
        s_red[t] = bk;
        __syncthreads();
        for (int s = TPP >> 1; s > 0; s >>= 1) {
            if ((sub < s) && p < P) {
                unsigned long long o = s_red[t + s];
                if (o < s_red[t]) s_red[t] = o;
            }
            __syncthreads();
        }
        if (t < P) s_idx[t] = (int)(unsigned int)(s_red[t * TPP] & 0xffffffffull);
    }
    if (t < HH) {
        double src = (t + 0.5) * (double)pn / 16.0 - 0.5;
        double fi = floor(src); int i0 = (int)fi; double tt = src - fi;
        #pragma unroll
        for (int k = 0; k < 4; ++k) {
            int j = i0 - 1 + k; j = j < 0 ? 0 : (j > pn - 1 ? pn - 1 : j);
            s_j[t][k] = j;
            s_w[t][k] = (float)cubicw((double)(k - 1) - tt);
        }
    }
    {
        const float* src = pw + ((size_t)(kphi * CC + cog * 8)) * CC * 9;
        for (int i = t; i < 8 * CC * 9; i += 1024) {
            int col = i / (CC * 9);
            int r   = i - col * (CC * 9);
            s_pw[r * 8 + col] = src[i];
        }
    }
    __syncthreads();

    // ---- phase A: vertical bicubic + gather; quarter handles 8 channels ----
    if (tl < HH * pn) {
        int h = tl / pn, q = tl % pn;
        int cbase = qt * 8;
        float acc[8];
        #pragma unroll
        for (int c = 0; c < 8; ++c) acc[c] = 0.f;
        #pragma unroll
        for (int k = 0; k < 4; ++k) {
            float wv = s_w[h][k];
            if (wv == 0.0f) continue;   // exact-zero tap contributes exactly +0
            int row = s_idx[s_j[h][k] * pn + q];
            const float4* er = (const float4*)(E + (size_t)row * CC + cbase);
            #pragma unroll
            for (int c4 = 0; c4 < 2; ++c4) {
                float4 e4 = er[c4];
                acc[c4*4+0] = fmaf(wv, e4.x, acc[c4*4+0]);
                acc[c4*4+1] = fmaf(wv, e4.y, acc[c4*4+1]);
                acc[c4*4+2] = fmaf(wv, e4.z, acc[c4*4+2]);
                acc[c4*4+3] = fmaf(wv, e4.w, acc[c4*4+3]);
            }
        }
        #pragma unroll
        for (int c = 0; c < 8; ++c)
            s_buf[((cbase + c) * HH + h) * pn + q] = acc[c];
    }
    __syncthreads();

    // ---- phase B: (c,h)-row threads; contiguous row load, 16 outputs ----
    {
        bool act = (t < CC * HH);
        int c = t >> 4, h = t & 15;
        float rowv[16];
        if (act) {
            const float* src = &s_buf[(c * HH + h) * pn];
            for (int j = 0; j < pn; ++j) rowv[j] = src[j];
        }
        __syncthreads();   // all tmp reads complete before aliased writes
        if (act) {
            float* dst = &s_buf[(c * 18 + h + 1) * 20];
            dst[0] = 0.f;
            #pragma unroll
            for (int w = 0; w < HH; ++w) {
                float acc = 0.f;
                #pragma unroll
                for (int k = 0; k < 4; ++k)
                    acc = fmaf(s_w[w][k], rowv[s_j[w][k]], acc);
                dst[w + 1] = acc;
            }
            dst[17] = 0.f; dst[18] = 0.f; dst[19] = 0.f;
            if (h == 0) {
                float* d0 = &s_buf[(c * 18) * 20];
                #pragma unroll
                for (int i = 0; i < 20; ++i) d0[i] = 0.f;
            }
            if (h == 15) {
                float* d1 = &s_buf[(c * 18 + 17) * 20];
                #pragma unroll
                for (int i = 0; i < 20; ++i) d1[i] = 0.f;
            }
        }
    }
    __syncthreads();

    // ---- conv 3x3: ci quarter per thread; 3-way s_part combine ----
    int col = tl >> 5;
    int co  = cog * 8 + col;
    int s   = tl & 31;
    int h   = s >> 1;
    int w0  = (s & 1) * 8;
    float acc[8];
    float bias = pb[kphi * CC + co];
    #pragma unroll
    for (int o = 0; o < 8; ++o) acc[o] = (qt == 0) ? bias : 0.f;
    int ci0 = qt * 8;
    for (int ci = ci0; ci < ci0 + 8; ++ci) {
        const float* wb = &s_pw[(ci * 9) * 8 + col];
        #pragma unroll
        for (int kh = 0; kh < 3; ++kh) {
            const float4* xr = (const float4*)&s_buf[(ci * 18 + h + kh) * 20 + w0];
            float4 a0 = xr[0], a1 = xr[1], a2 = xr[2];
            float xf[12] = {a0.x, a0.y, a0.z, a0.w, a1.x, a1.y, a1.z, a1.w,
                            a2.x, a2.y, a2.z, a2.w};
            float k0 = wb[(kh*3+0)*8], k1 = wb[(kh*3+1)*8], k2 = wb[(kh*3+2)*8];
            #pragma unroll
            for (int o = 0; o < 8; ++o)
                acc[o] += xf[o] * k0 + xf[o+1] * k1 + xf[o+2] * k2;
        }
    }
    if (qt != 0) {
        #pragma unroll
        for (int o = 0; o < 8; ++o) s_part[((qt - 1) * 256 + tl) * 9 + o] = acc[o];
    }
    __syncthreads();

    // ---- epilogue (quarter 0 only): combine + update f_hat / f_rest ----
    float4 r0, r1;
    if (qt == 0) {
        #pragma unroll
        for (int p3 = 0; p3 < 3; ++p3)
            #pragma unroll
            for (int o = 0; o < 8; ++o) acc[o] += s_part[(p3 * 256 + tl) * 9 + o];
        size_t base = ((size_t)(b * CC + co) * HH + h) * HH + w0;
        float hf[8];
        #pragma unroll
        for (int o = 0; o < 8; ++o) {
            float hv = s_buf[(co * 18 + h + 1) * 20 + w0 + o + 1];
            hf[o] = 0.5f * hv + 0.5f * acc[o];
        }
        float4* fh = (float4*)(f_hat + base);
        float4* fr = (float4*)(f_rest + base);
        float4 v0 = fh[0], v1 = fh[1];
        v0.x += hf[0]; v0.y += hf[1]; v0.z += hf[2]; v0.w += hf[3];
        v1.x += hf[4]; v1.y += hf[5]; v1.z += hf[6]; v1.w += hf[7];
        fh[0] = v0; fh[1] = v1;
        r0 = fr[0]; r1 = fr[1];
        r0.x -= hf[0]; r0.y -= hf[1]; r0.z -= hf[2]; r0.w -= hf[3];
        r1.x -= hf[4]; r1.y -= hf[5]; r1.z -= hf[6]; r1.w -= hf[7];
        fr[0] = r0; fr[1] = r1;
    }

    // ---- emit next scale's z rows ----
    if (pnn > 0) {
        __syncthreads();   // all s_buf reads complete
        float* fn = s_buf; // reuse: fnew[col][16][16]
        if (qt == 0) {
            float* d = &fn[(col * HH + h) * HH + w0];
            d[0] = r0.x; d[1] = r0.y; d[2] = r0.z; d[3] = r0.w;
            d[4] = r1.x; d[5] = r1.y; d[6] = r1.z; d[7] = r1.w;
        }
        __syncthreads();
        int P2 = pnn * pnn;
        for (int i = t; i < P2 * 8; i += 1024) {
            int cl = i & 7, pq = i >> 3;
            int q2 = pq % pnn, p2 = pq / pnn;
            int sp = (p2 * HH) / pnn, ep = ((p2 + 1) * HH + pnn - 1) / pnn;
            int sq = (q2 * HH) / pnn, eq = ((q2 + 1) * HH + pnn - 1) / pnn;
            float wgt = 1.0f / ((float)(ep - sp) * (float)(eq - sq));
            float sum = 0.f;
            for (int h2 = sp; h2 < ep; ++h2)
                for (int w2 = sq; w2 < eq; ++w2)
                    sum += fn[(cl * HH + h2) * HH + w2];
            z_next[((size_t)(b * P2 + pq)) * CC + cog * 8 + cl] = sum * wgt;
        }
    }
}

extern "C" void kernel_launch(void* const* d_in, const int* in_sizes, int n_in,
                              void* d_out, int out_size, void* d_ws, size_t ws_size,
                              hipStream_t stream) {
    const float* f  = (const float*)d_in[0];
    const float* E  = (const float*)d_in[1];
    const float* pw = (const float*)d_in[2];
    const float* pb = (const float*)d_in[3];
    float* out = (float*)d_out;

    const size_t need_mf = (size_t)(NTOT + VV) * 4 + (size_t)524288 * 8 +
                           (size_t)524288 * 4 + (size_t)VV * 48 * 4;
    const bool use_mf = (ws_size >= need_mf);

    float* wsf    = (float*)d_ws;
    float* f_rest = wsf;
    float* e2     = wsf + (size_t)NTOT;
    unsigned long long* bestk = (unsigned long long*)(e2 + VV);
    float* z      = (float*)(bestk + 524288);
    float* es     = use_mf ? (z + 524288) : (float*)0;

    int phik[10];
    {
        double start = 1.0 / 3.0 / 4.0;
        double stop  = 1.0 - 1.0 / 3.0 / 4.0;
        double step  = (stop - start) / 3.0;
        double ticks[4];
        for (int i = 0; i < 4; ++i) ticks[i] = (double)i * step + start;
        ticks[3] = stop;
        for (int si = 0; si < 10; ++si) {
            double s = (double)si / 9.0;
            int bk = 0; double bd = fabs(ticks[0] - s);
            for (int tq = 1; tq < 4; ++tq) {
                double d2 = fabs(ticks[tq] - s);
                if (d2 < bd) { bd = d2; bk = tq; }
            }
            phik[si] = bk;
        }
    }

    static const int pns[10]  = {1, 2, 3, 4, 5, 6, 8, 10, 13, 16};
    static const int grpS[10] = {256, 128, 64, 32, 32, 16, 0, 0, 0, 0};
    static const int grpF[10] = {0, 0, 0, 0, 0, 0, 128, 64, 32, 32};
    static const int grpM[10] = {0, 0, 0, 0, 0, 0, 64, 64, 32, 32};

    init_k<<<(NTOT + 255) / 256, 256, 0, stream>>>(f, E, f_rest, out, e2, z, es);

    for (int si = 0; si < 10; ++si) {
        int pn = pns[si];
        int P = pn * pn;
        int M = BB * P;
        int G, TPP;
        if (pn <= 6) {
            int grp = grpS[si];
            G = grp * 4;
            int gsz = VV / G;
            argsmall_k<<<dim3(P, grp), 256, 0, stream>>>(z, E, e2, bestk, M, G, gsz);
        } else if (use_mf) {
            G = grpM[si];
            int gsz = VV / G;
            int bx = (M + 127) / 128;
            argmf_k<<<dim3(bx, G), 256, 0, stream>>>(z, es, e2, bestk, M, G, gsz);
        } else {
            G = grpF[si];
            int gsz = VV / G;
            int bx = (M + 511) / 512;
            argbig_k<<<dim3(bx, G), 256, 0, stream>>>(z, E, e2, bestk, M, G, gsz);
        }
        TPP = 1;
        while (TPP * 2 * P <= 1024) TPP *= 2;
        int pnn = (si < 9) ? pns[si + 1] : 0;
        fuse_k<<<dim3(4, BB), 1024, 0, stream>>>(bestk, E, pw, pb,
                                                 out, f_rest, z,
                                                 pn, G, TPP, phik[si], pnn);
    }
}